// Round 1
// baseline (1880.516 us; speedup 1.0000x reference)
//
#include <hip/hip_runtime.h>
#include <math.h>

#define NN    192      // N = state size = OUT
#define NIN   64       // input size
#define NT    32       // timesteps
#define DTC   0.1f
#define BLK   256
#define NWAVE 4
#define RPW   48       // rows per wave (192/4)
#define CPL   3        // cols per lane (192/64)

struct WS {
  float hbuf[2][NN];     // ping-pong tanh(a_t)
  float e_g[NN];
  float k_g[NN];
  float Wot[NN][NN];     // W_out transposed: Wot[j][i] = W_out[i][j]
  float Wrt[NN][NN];     // W_rec transposed: Wrt[j][i] = W_rec[i][j]
  float Po [NN][NN];     // P_output (kept exactly symmetric)
  int   bar[NT + 1];     // grid barriers (init + per step)
  int   cnt[NT];         // e/k readiness counters
};

__device__ __forceinline__ float warp_sum(float v) {
  #pragma unroll
  for (int o = 32; o > 0; o >>= 1) v += __shfl_down(v, o, 64);
  return v;
}

// full-block reduction, result broadcast to all threads
__device__ __forceinline__ float block_sum_bcast(float v, float* red, int tid) {
  v = warp_sum(v);
  __syncthreads();
  if ((tid & 63) == 0) red[tid >> 6] = v;
  __syncthreads();
  float s = red[0] + red[1] + red[2] + red[3];
  __syncthreads();   // protect red[] for next reuse
  return s;
}

__device__ __forceinline__ void grid_barrier(int* ctr, int nblk) {
  __threadfence();                 // publish this block's writes (agent scope)
  __syncthreads();
  if (threadIdx.x == 0) {
    __hip_atomic_fetch_add(ctr, 1, __ATOMIC_ACQ_REL, __HIP_MEMORY_SCOPE_AGENT);
    long it = 0;
    while (__hip_atomic_load(ctr, __ATOMIC_RELAXED, __HIP_MEMORY_SCOPE_AGENT) < nblk) {
      __builtin_amdgcn_s_sleep(2);
      if (++it > 50000000L) break;   // hang guard (wrong results, no deadlock)
    }
  }
  __syncthreads();
  __threadfence();                 // acquire: invalidate stale cached lines
}

extern "C" __global__ void __launch_bounds__(BLK, 1)
force_persistent(const float* __restrict__ x,   const float* __restrict__ y,
                 const float* __restrict__ Win, const float* __restrict__ Wrec,
                 const float* __restrict__ Wout,const float* __restrict__ a0,
                 const float* __restrict__ Pout,const float* __restrict__ Pgg,
                 float* __restrict__ out, WS* __restrict__ ws)
{
  const int b    = blockIdx.x;      // slice / row owner
  const int tid  = threadIdx.x;
  const int w    = tid >> 6;
  const int l    = tid & 63;
  const int nblk = gridDim.x;

  __shared__ float th[NN];    // tanh(a_{t-1})
  __shared__ float hs[NN];    // h_t
  __shared__ float PhS[NN];
  __shared__ float es[NN];
  __shared__ float ks[NN];
  __shared__ float red[NWAVE];

  float S[RPW][CPL];          // register-resident P_GG slice b

  // ---------------- init ----------------
  {
    const float* slice = Pgg + (size_t)b * NN * NN;
    #pragma unroll
    for (int rr = 0; rr < RPW; ++rr) {
      const int j = w * RPW + rr;
      #pragma unroll
      for (int m = 0; m < CPL; ++m)
        S[rr][m] = slice[j * NN + (l + 64 * m)];
    }
    for (int i = tid; i < NN; i += BLK) {
      ws->Wot[b][i] = Wout[i * NN + b];
      ws->Wrt[b][i] = Wrec[i * NN + b];
      ws->Po [b][i] = Pout[b * NN + i];
    }
    if (tid == 0) ws->hbuf[0][b] = tanhf(a0[b]);
  }
  float a_reg = a0[b];
  grid_barrier(&ws->bar[0], nblk);

  for (int t = 0; t < NT; ++t) {
    const int pcur = t & 1;          // holds tanh(a_{t-1})
    const int pnxt = (t + 1) & 1;    // will hold h_t

    // ---- Phase A: a_t = (1-dt)a + dt(tanh(a_{t-1})@W_r + x_t@W_in); h_t = tanh(a_t)
    for (int i = tid; i < NN; i += BLK) th[i] = ws->hbuf[pcur][i];
    __syncthreads();
    float pa = 0.f;
    for (int j = tid; j < NN; j += BLK) pa += th[j] * ws->Wrt[b][j];
    if (tid < NIN) pa += x[t * NIN + tid] * Win[tid * NN + b];
    const float ssum = block_sum_bcast(pa, red, tid);
    a_reg = (1.f - DTC) * a_reg + DTC * ssum;
    const float htb = tanhf(a_reg);
    if (tid == 0) ws->hbuf[pnxt][b] = htb;
    grid_barrier(&ws->bar[t + 1], nblk);

    // ---- Phase B: z_b, e_b, k_b (all own-row reads; z uses pre-update W_o)
    for (int i = tid; i < NN; i += BLK) hs[i] = ws->hbuf[pnxt][i];
    __syncthreads();
    float pz = 0.f, pk = 0.f;
    for (int i = tid; i < NN; i += BLK) {
      const float hv = hs[i];
      pz += hv * ws->Wot[b][i];
      pk += ws->Po[b][i] * hv;
    }
    const float z_b = block_sum_bcast(pz, red, tid);
    const float k_b = block_sum_bcast(pk, red, tid);
    if (tid == 0) {
      out[t * NN + b] = z_b;
      ws->e_g[b] = z_b - y[t * NN + b];
      ws->k_g[b] = k_b;
      __threadfence();
      __hip_atomic_fetch_add(&ws->cnt[t], 1, __ATOMIC_RELEASE, __HIP_MEMORY_SCOPE_AGENT);
    }

    // ---- Phase C: Ph = S @ h from registers (slice symmetric => htP == Ph)
    float hl[CPL];
    #pragma unroll
    for (int m = 0; m < CPL; ++m) hl[m] = hs[l + 64 * m];
    #pragma unroll
    for (int rr = 0; rr < RPW; ++rr) {
      float p = S[rr][0] * hl[0] + S[rr][1] * hl[1] + S[rr][2] * hl[2];
      #pragma unroll
      for (int o = 32; o > 0; o >>= 1) p += __shfl_xor(p, o, 64);
      if (l == 0) PhS[w * RPW + rr] = p;
    }
    __syncthreads();
    float pp = 0.f;
    for (int j = tid; j < NN; j += BLK) pp += PhS[j] * hs[j];
    const float hPh  = block_sum_bcast(pp, red, tid);
    const float rden = 1.f / (1.f + hPh);

    // ---- wait for full e,k (overlapped with Phase C work above)
    if (tid == 0) {
      long it = 0;
      while (__hip_atomic_load(&ws->cnt[t], __ATOMIC_RELAXED, __HIP_MEMORY_SCOPE_AGENT) < nblk) {
        __builtin_amdgcn_s_sleep(2);
        if (++it > 50000000L) break;
      }
    }
    __syncthreads();
    __threadfence();
    for (int i = tid; i < NN; i += BLK) { es[i] = ws->e_g[i]; ks[i] = ws->k_g[i]; }
    __syncthreads();

    // ---- Phase D: row updates + slice update
    float ph = 0.f;
    for (int j = tid; j < NN; j += BLK) ph += ks[j] * hs[j];
    const float hk = block_sum_bcast(ph, red, tid);
    const float c  = 1.f / (1.f + hk);
    const float kb = ks[b], eb = es[b];
    for (int i = tid; i < NN; i += BLK) {
      ws->Po [b][i] -= c * kb * ks[i];              // P_o -= c k k^T (symmetric)
      ws->Wot[b][i] -= c * ks[i] * eb;              // W_o -= (c k) e^T  (P_o' h = c k)
      ws->Wrt[b][i] -= rden * PhS[i] * es[i];       // W_r col b -= Ph2[b,:]*e  (Ph2 = Ph/(1+hPh))
    }
    float phk[CPL];
    #pragma unroll
    for (int m = 0; m < CPL; ++m) phk[m] = PhS[l + 64 * m];
    #pragma unroll
    for (int rr = 0; rr < RPW; ++rr) {
      const float rv = rden * PhS[w * RPW + rr];
      #pragma unroll
      for (int m = 0; m < CPL; ++m) S[rr][m] -= rv * phk[m];
    }
    // next iteration's Phase A only reads own-row Wrt (same-thread elements) and
    // hbuf via the grid barrier -- no extra sync needed here.
  }
}

extern "C" void kernel_launch(void* const* d_in, const int* in_sizes, int n_in,
                              void* d_out, int out_size, void* d_ws, size_t ws_size,
                              hipStream_t stream) {
  const float* x    = (const float*)d_in[0];
  const float* y    = (const float*)d_in[1];
  const float* Win  = (const float*)d_in[2];
  const float* Wrec = (const float*)d_in[3];
  const float* Wout = (const float*)d_in[4];
  const float* a0   = (const float*)d_in[5];
  const float* Pout = (const float*)d_in[6];
  const float* Pgg  = (const float*)d_in[7];
  float* out = (float*)d_out;
  WS* ws = (WS*)d_ws;
  (void)in_sizes; (void)n_in; (void)out_size; (void)ws_size;

  // zero the barrier/counter region every call (deterministic across graph replays)
  hipMemsetAsync(&ws->bar[0], 0, sizeof(int) * (2 * NT + 1), stream);
  force_persistent<<<NN, BLK, 0, stream>>>(x, y, Win, Wrec, Wout, a0, Pout, Pgg, out, ws);
}

// Round 2
// 984.013 us; speedup vs baseline: 1.9111x; 1.9111x over previous
//
#include <hip/hip_runtime.h>
#include <math.h>

#define NN   192     // N = state = OUT, also grid size
#define NIN  64
#define NT   32
#define BLK  192     // 3 waves; thread j owns row j of this block's P_GG slice
#define NW   3

// 8 spread counters per step, each on its own 64B line (16 ints apart)
struct WS {
  float hbuf[2][NN];
  float e_g[NN];
  float k_g[NN];
  int   cnt_h [NT][128];
  int   cnt_ek[NT][128];
};

#define REP48(M) M(0)M(1)M(2)M(3)M(4)M(5)M(6)M(7)M(8)M(9)M(10)M(11)M(12)M(13)M(14)M(15)M(16)M(17)M(18)M(19)M(20)M(21)M(22)M(23)M(24)M(25)M(26)M(27)M(28)M(29)M(30)M(31)M(32)M(33)M(34)M(35)M(36)M(37)M(38)M(39)M(40)M(41)M(42)M(43)M(44)M(45)M(46)M(47)

__device__ __forceinline__ float block_sum(float v, float* red, int w, int l) {
  #pragma unroll
  for (int o = 32; o > 0; o >>= 1) v += __shfl_down(v, o, 64);
  __syncthreads();                 // protect red[] from previous use
  if (l == 0) red[w] = v;
  __syncthreads();
  return red[0] + red[1] + red[2];
}

// wait until the 8 spread counters sum to NN; then fence so subsequent reads are fresh
__device__ __forceinline__ void wait192(int* base, int w, int l) {
  if (w == 0) {
    long g = 0;
    while (true) {
      int v = (l < 8) ? __hip_atomic_load(base + (l << 4), __ATOMIC_RELAXED,
                                          __HIP_MEMORY_SCOPE_AGENT) : 0;
      v += __shfl_xor(v, 1, 64);
      v += __shfl_xor(v, 2, 64);
      v += __shfl_xor(v, 4, 64);
      v  = __shfl(v, 0, 64);
      if (v >= NN) break;
      __builtin_amdgcn_s_sleep(1);
      if (++g > 30000000L) break;   // hang guard
    }
  }
  __syncthreads();
  __threadfence();                  // acquire: invalidate L1/L2 (dirty set is tiny)
}

extern "C" __global__ void __launch_bounds__(BLK, 1)
force_persistent(const float* __restrict__ x,   const float* __restrict__ y,
                 const float* __restrict__ Win, const float* __restrict__ Wrec,
                 const float* __restrict__ Wout,const float* __restrict__ a0,
                 const float* __restrict__ Pout,const float* __restrict__ Pgg,
                 float* __restrict__ out, WS* __restrict__ ws)
{
  const int b   = blockIdx.x;
  const int tid = threadIdx.x;
  const int w   = tid >> 6;
  const int l   = tid & 63;

  __shared__ float red[NW];
  __shared__ __align__(16) float phS[NN];
  __shared__ float xwS[NT];
  __shared__ float yS [NT];

  // ---- P_GG slice b, row `tid`, as 48 named float4 registers (no alloca) ----
  #define SDECL(r) float4 s##r;
  REP48(SDECL)
  {
    const float4* srow = (const float4*)(Pgg + (size_t)b * NN * NN + (size_t)tid * NN);
    #define SLOAD(r) s##r = srow[r];
    REP48(SLOAD)
  }

  // per-thread-owned elements of row/col b of the small matrices (never hit global again)
  float wrt = Wrec[tid * NN + b];    // W_rec[tid][b]
  float wot = Wout[tid * NN + b];    // W_out[tid][b]
  float po  = Pout[b * NN + tid];    // P_o[b][tid]
  float hprev = tanhf(a0[tid]);      // full h_{-1} is local: a0 is an input
  float a_reg = a0[b];

  if (tid < NT) {
    float acc = 0.f;
    #pragma unroll 1
    for (int i = 0; i < NIN; ++i) acc += x[tid * NIN + i] * Win[i * NN + b];
    xwS[tid] = acc;                  // (x_t @ W_in)[b]
    yS [tid] = y[tid * NN + b];
  }
  __syncthreads();

  #pragma unroll 1
  for (int t = 0; t < NT; ++t) {
    const int slot = t & 1;

    // ---- A: a_t, h_t[b]; publish h ----
    const float ssum = block_sum(hprev * wrt, red, w, l);
    a_reg = 0.9f * a_reg + 0.1f * (ssum + xwS[t]);
    const float hb = tanhf(a_reg);
    if (tid == 0) {
      ws->hbuf[slot][b] = hb;
      __hip_atomic_fetch_add(&ws->cnt_h[t][(b & 7) << 4], 1,
                             __ATOMIC_RELEASE, __HIP_MEMORY_SCOPE_AGENT);
    }
    wait192(&ws->cnt_h[t][0], w, l);
    const float h_own = ws->hbuf[slot][tid];

    // ---- B: z_b, k_b from own elements; publish e,k ----
    const float zb = block_sum(h_own * wot, red, w, l);
    const float kb = block_sum(po * h_own, red, w, l);
    if (tid == 0) {
      out[t * NN + b] = zb;
      ws->e_g[b] = zb - yS[t];
      ws->k_g[b] = kb;
      __hip_atomic_fetch_add(&ws->cnt_ek[t][(b & 7) << 4], 1,
                             __ATOMIC_RELEASE, __HIP_MEMORY_SCOPE_AGENT);
    }

    // ---- C: Ph[tid] = S_row . h  (192 FMA, h via uniform float4 loads) ----
    const float4* h4 = (const float4*)(ws->hbuf[slot]);
    float p = 0.f;
    #define PHC(r) { const float4 hv = h4[r]; \
                     p += s##r.x*hv.x + s##r.y*hv.y + s##r.z*hv.z + s##r.w*hv.w; }
    REP48(PHC)
    const float hPh  = block_sum(p * h_own, red, w, l);
    const float rden = 1.f / (1.f + hPh);
    const float rv   = rden * p;     // rden * Ph[tid]

    // ---- D: S -= (rden*Ph[j]) * Ph[k]  (overlaps the e/k exchange) ----
    phS[tid] = p;
    __syncthreads();
    const float4* ph4 = (const float4*)phS;
    #define PHD(r) { const float4 pv = ph4[r]; \
                     s##r.x -= rv*pv.x; s##r.y -= rv*pv.y; \
                     s##r.z -= rv*pv.z; s##r.w -= rv*pv.w; }
    REP48(PHD)

    // ---- wait for e,k; small row updates ----
    wait192(&ws->cnt_ek[t][0], w, l);
    const float e_own = ws->e_g[tid];
    const float k_own = ws->k_g[tid];
    const float e_b   = ws->e_g[b];
    const float k_b   = ws->k_g[b];
    const float hk = block_sum(k_own * h_own, red, w, l);
    const float c  = 1.f / (1.f + hk);
    po  -= c * k_b * k_own;          // P_o[b][i] -= c k_b k_i
    wot -= c * k_own * e_b;          // W_o[i][b] -= c k_i e_b
    wrt -= rv * e_own;               // W_r[i][b] -= rden Ph[i] e_i
    hprev = h_own;
  }
}

extern "C" void kernel_launch(void* const* d_in, const int* in_sizes, int n_in,
                              void* d_out, int out_size, void* d_ws, size_t ws_size,
                              hipStream_t stream) {
  const float* x    = (const float*)d_in[0];
  const float* y    = (const float*)d_in[1];
  const float* Win  = (const float*)d_in[2];
  const float* Wrec = (const float*)d_in[3];
  const float* Wout = (const float*)d_in[4];
  const float* a0   = (const float*)d_in[5];
  const float* Pout = (const float*)d_in[6];
  const float* Pgg  = (const float*)d_in[7];
  float* out = (float*)d_out;
  WS* ws = (WS*)d_ws;
  (void)in_sizes; (void)n_in; (void)out_size; (void)ws_size;

  // zero only the counters each call (deterministic across graph replays)
  hipMemsetAsync(&ws->cnt_h[0][0], 0, sizeof(int) * 2 * NT * 128, stream);
  force_persistent<<<NN, BLK, 0, stream>>>(x, y, Win, Wrec, Wout, a0, Pout, Pgg, out, ws);
}

// Round 3
// 199.473 us; speedup vs baseline: 9.4274x; 4.9331x over previous
//
#include <hip/hip_runtime.h>
#include <math.h>

#define NN   192     // N = state = OUT, grid size
#define NIN  64
#define NT   32
#define BLK  192     // 3 waves; thread j owns row j of this block's P_GG slice
#define NW   3

typedef unsigned long long u64;

// All cross-block traffic is tagged 64-bit relaxed agent-scope atomics.
// No fences, no counters -> no buffer_wbl2 / buffer_inv anywhere.
struct WS {
  u64 hslot[NN];   // (tag<<32)|bits(h_b)
  u64 eslot[NN];   // (tag<<32)|bits(e_b)
  u64 kslot[NN];   // (tag<<32)|bits(k_b)
};

#define REP48(M) M(0)M(1)M(2)M(3)M(4)M(5)M(6)M(7)M(8)M(9)M(10)M(11)M(12)M(13)M(14)M(15)M(16)M(17)M(18)M(19)M(20)M(21)M(22)M(23)M(24)M(25)M(26)M(27)M(28)M(29)M(30)M(31)M(32)M(33)M(34)M(35)M(36)M(37)M(38)M(39)M(40)M(41)M(42)M(43)M(44)M(45)M(46)M(47)

__device__ __forceinline__ u64 packf(float v, int tag) {
  return ((u64)(unsigned)tag << 32) | (u64)__float_as_uint(v);
}

__device__ __forceinline__ float poll_slot(u64* p, int tag) {
  u64 v; long g = 0;
  while (true) {
    v = __hip_atomic_load(p, __ATOMIC_RELAXED, __HIP_MEMORY_SCOPE_AGENT);
    if ((int)(v >> 32) == tag) break;
    __builtin_amdgcn_s_sleep(1);
    if (++g > 30000000L) break;    // hang guard: wrong answer, never deadlock
  }
  return __uint_as_float((unsigned)v);
}

__device__ __forceinline__ float block_sum(float v, float* red, int w, int l) {
  #pragma unroll
  for (int o = 32; o > 0; o >>= 1) v += __shfl_down(v, o, 64);
  __syncthreads();                 // protect red[] from previous use
  if (l == 0) red[w] = v;
  __syncthreads();
  return red[0] + red[1] + red[2];
}

__device__ __forceinline__ float2 block_sum2(float va, float vb, float (*red)[NW],
                                             int w, int l) {
  #pragma unroll
  for (int o = 32; o > 0; o >>= 1) {
    va += __shfl_down(va, o, 64);
    vb += __shfl_down(vb, o, 64);
  }
  __syncthreads();
  if (l == 0) { red[0][w] = va; red[1][w] = vb; }
  __syncthreads();
  return make_float2(red[0][0] + red[0][1] + red[0][2],
                     red[1][0] + red[1][1] + red[1][2]);
}

extern "C" __global__ void __launch_bounds__(BLK, 1)
force_persistent(const float* __restrict__ x,   const float* __restrict__ y,
                 const float* __restrict__ Win, const float* __restrict__ Wrec,
                 const float* __restrict__ Wout,const float* __restrict__ a0,
                 const float* __restrict__ Pout,const float* __restrict__ Pgg,
                 float* __restrict__ out, WS* __restrict__ ws)
{
  const int b   = blockIdx.x;
  const int tid = threadIdx.x;
  const int w   = tid >> 6;
  const int l   = tid & 63;

  __shared__ float red2[2][NW];
  __shared__ __align__(16) float hsS[NN];
  __shared__ __align__(16) float phS[NN];
  __shared__ float2 ekS[NN];
  __shared__ float xwS[NT];
  __shared__ float yS [NT];

  // ---- init: xw[t] = (x_t @ W_in)[b] via wave-0 parallel dot; y column ----
  if (w == 0) {
    const float wv = Win[l * NN + b];       // lane l owns input index l (NIN==64)
    float c[NT];
    #pragma unroll
    for (int t2 = 0; t2 < NT; ++t2) c[t2] = x[t2 * NIN + l] * wv;
    #pragma unroll
    for (int o = 32; o > 0; o >>= 1) {
      #pragma unroll
      for (int t2 = 0; t2 < NT; ++t2) c[t2] += __shfl_xor(c[t2], o, 64);
    }
    if (l == 0) {
      #pragma unroll
      for (int t2 = 0; t2 < NT; ++t2) xwS[t2] = c[t2];
    }
  } else if (w == 1 && l < NT) {
    yS[l] = y[l * NN + b];
  }

  // per-thread-owned elements (never touch global again)
  float wrt = Wrec[tid * NN + b];    // W_rec[tid][b]
  float wot = Wout[tid * NN + b];    // W_out[tid][b]
  float po  = Pout[b * NN + tid];    // P_o[b][tid]
  float hprev = tanhf(a0[tid]);
  float a_reg = a0[b];

  // ---- P_GG slice b, row `tid`, as 48 named float4 registers ----
  #define SDECL(r) float4 s##r;
  REP48(SDECL)
  {
    const float4* srow = (const float4*)(Pgg + (size_t)b * NN * NN + (size_t)tid * NN);
    #define SLOAD(r) s##r = srow[r];
    REP48(SLOAD)
  }
  __syncthreads();   // xwS / yS ready

  #pragma unroll 1
  for (int t = 0; t < NT; ++t) {
    const int tag = t + 1;

    // ---- A: a_t, publish h_b ----
    const float ssum = block_sum(hprev * wrt, red2[0], w, l);
    a_reg = 0.9f * a_reg + 0.1f * (ssum + xwS[t]);
    if (tid == 0)
      __hip_atomic_store(&ws->hslot[b], packf(tanhf(a_reg), tag),
                         __ATOMIC_RELAXED, __HIP_MEMORY_SCOPE_AGENT);

    // ---- poll h (each thread its own word), broadcast via LDS ----
    const float h_own = poll_slot(&ws->hslot[tid], tag);
    hsS[tid] = h_own;

    // ---- B: z_b, k_b (one dual reduction); publish e,k ----
    const float2 zk = block_sum2(h_own * wot, po * h_own, red2, w, l);
    if (tid == 0) {
      out[t * NN + b] = zk.x;
      __hip_atomic_store(&ws->eslot[b], packf(zk.x - yS[t], tag),
                         __ATOMIC_RELAXED, __HIP_MEMORY_SCOPE_AGENT);
      __hip_atomic_store(&ws->kslot[b], packf(zk.y, tag),
                         __ATOMIC_RELAXED, __HIP_MEMORY_SCOPE_AGENT);
    }

    // ---- C: Ph[tid] = S_row . h  (S in regs, h broadcast from LDS) ----
    const float4* h4 = (const float4*)hsS;
    float p = 0.f;
    #define PHC(r) { const float4 hv = h4[r]; \
                     p += s##r.x*hv.x + s##r.y*hv.y + s##r.z*hv.z + s##r.w*hv.w; }
    REP48(PHC)
    const float hPh = block_sum(p * h_own, red2[0], w, l);
    const float rv  = p / (1.f + hPh);     // rden * Ph[tid]

    // ---- D: S -= rv * Ph  (hides the e/k exchange latency) ----
    phS[tid] = p;
    __syncthreads();
    const float4* ph4 = (const float4*)phS;
    #define PHD(r) { const float4 pv = ph4[r]; \
                     s##r.x -= rv*pv.x; s##r.y -= rv*pv.y; \
                     s##r.z -= rv*pv.z; s##r.w -= rv*pv.w; }
    REP48(PHD)

    // ---- poll e,k; small row updates ----
    const float e_own = poll_slot(&ws->eslot[tid], tag);
    const float k_own = poll_slot(&ws->kslot[tid], tag);
    ekS[tid] = make_float2(e_own, k_own);
    const float hk = block_sum(k_own * h_own, red2[0], w, l);  // barrier makes ekS visible
    const float2 ekb = ekS[b];
    const float c1 = 1.f / (1.f + hk);
    po  -= c1 * ekb.y * k_own;         // P_o[b][i] -= c k_b k_i
    wot -= c1 * k_own * ekb.x;         // W_o[i][b] -= c k_i e_b
    wrt -= rv * e_own;                 // W_r[i][b] -= rden Ph[i] e_i
    hprev = h_own;
  }
}

extern "C" void kernel_launch(void* const* d_in, const int* in_sizes, int n_in,
                              void* d_out, int out_size, void* d_ws, size_t ws_size,
                              hipStream_t stream) {
  const float* x    = (const float*)d_in[0];
  const float* y    = (const float*)d_in[1];
  const float* Win  = (const float*)d_in[2];
  const float* Wrec = (const float*)d_in[3];
  const float* Wout = (const float*)d_in[4];
  const float* a0   = (const float*)d_in[5];
  const float* Pout = (const float*)d_in[6];
  const float* Pgg  = (const float*)d_in[7];
  float* out = (float*)d_out;
  WS* ws = (WS*)d_ws;
  (void)in_sizes; (void)n_in; (void)out_size; (void)ws_size;

  // reset all tags each call (deterministic across graph replays)
  hipMemsetAsync(ws, 0, sizeof(WS), stream);
  force_persistent<<<NN, BLK, 0, stream>>>(x, y, Win, Wrec, Wout, a0, Pout, Pgg, out, ws);
}

// Round 4
// 139.174 us; speedup vs baseline: 13.5120x; 1.4333x over previous
//
#include <hip/hip_runtime.h>
#include <math.h>

#define NN   192     // N = state = OUT, grid size
#define NIN  64
#define NT   32
#define BLK  192     // 3 waves; thread j owns row j of this block's P_GG slice
#define NW   3

typedef unsigned long long u64;

// Cross-block traffic: tagged 64-bit relaxed agent-scope atomics (no fences).
struct WS {
  u64 hslot[NN];       // (tag<<32)|bits(h_b)
  u64 ekslot[NN][2];   // [0]=(tag,e_b)  [1]=(tag,k_b)
};

#define REP48(M) M(0)M(1)M(2)M(3)M(4)M(5)M(6)M(7)M(8)M(9)M(10)M(11)M(12)M(13)M(14)M(15)M(16)M(17)M(18)M(19)M(20)M(21)M(22)M(23)M(24)M(25)M(26)M(27)M(28)M(29)M(30)M(31)M(32)M(33)M(34)M(35)M(36)M(37)M(38)M(39)M(40)M(41)M(42)M(43)M(44)M(45)M(46)M(47)

__device__ __forceinline__ u64 packf(float v, unsigned tag) {
  return ((u64)tag << 32) | (u64)__float_as_uint(v);
}

__device__ __forceinline__ float poll_slot(u64* p, unsigned tag) {
  u64 v; long g = 0;
  while (true) {
    v = __hip_atomic_load(p, __ATOMIC_RELAXED, __HIP_MEMORY_SCOPE_AGENT);
    if ((unsigned)(v >> 32) == tag) break;
    __builtin_amdgcn_s_sleep(1);
    if (++g > 30000000L) break;    // hang guard
  }
  return __uint_as_float((unsigned)v);
}

__device__ __forceinline__ float2 poll_ek(u64* p, unsigned tag) {
  u64 va, vb; long g = 0;
  while (true) {
    va = __hip_atomic_load(p,     __ATOMIC_RELAXED, __HIP_MEMORY_SCOPE_AGENT);
    vb = __hip_atomic_load(p + 1, __ATOMIC_RELAXED, __HIP_MEMORY_SCOPE_AGENT);
    if (((unsigned)(va >> 32) == tag) & ((unsigned)(vb >> 32) == tag)) break;
    __builtin_amdgcn_s_sleep(1);
    if (++g > 30000000L) break;
  }
  return make_float2(__uint_as_float((unsigned)va), __uint_as_float((unsigned)vb));
}

// K-way fused block reduction. Butterfly in-wave, cross-wave via caller-supplied
// LDS buffer (parity-alternated by the caller -> no protective pre-barrier).
// Exactly ONE __syncthreads inside.
template <int K>
__device__ __forceinline__ void block_reduceK(float* v, float (*red)[NW], int w, int l) {
  #pragma unroll
  for (int o = 32; o > 0; o >>= 1) {
    #pragma unroll
    for (int q = 0; q < K; ++q) v[q] += __shfl_xor(v[q], o, 64);
  }
  if (l == 0) {
    #pragma unroll
    for (int q = 0; q < K; ++q) red[q][w] = v[q];
  }
  __syncthreads();
  #pragma unroll
  for (int q = 0; q < K; ++q) v[q] = red[q][0] + red[q][1] + red[q][2];
}

extern "C" __global__ void __launch_bounds__(BLK, 1)
force_persistent(const float* __restrict__ x,   const float* __restrict__ y,
                 const float* __restrict__ Win, const float* __restrict__ Wrec,
                 const float* __restrict__ Wout,const float* __restrict__ a0,
                 const float* __restrict__ Pout,const float* __restrict__ Pgg,
                 float* __restrict__ out, WS* __restrict__ ws)
{
  const int b   = blockIdx.x;
  const int tid = threadIdx.x;
  const int w   = tid >> 6;
  const int l   = tid & 63;

  __shared__ __align__(16) float hsS[NN];
  __shared__ __align__(16) float phS[NN];
  __shared__ float red5[2][5][NW];
  __shared__ float red3[2][3][NW];
  __shared__ float xwS[NT];
  __shared__ float yS [NT];

  // ---- init: xw[t] = (x_t @ W_in)[b] (wave0); y column (wave1) ----
  if (w == 0) {
    const float wv = Win[l * NN + b];        // lane l owns input index l (NIN==64)
    float c[NT];
    #pragma unroll
    for (int t2 = 0; t2 < NT; ++t2) c[t2] = x[t2 * NIN + l] * wv;
    #pragma unroll
    for (int o = 32; o > 0; o >>= 1) {
      #pragma unroll
      for (int t2 = 0; t2 < NT; ++t2) c[t2] += __shfl_xor(c[t2], o, 64);
    }
    if (l == 0) {
      #pragma unroll
      for (int t2 = 0; t2 < NT; ++t2) xwS[t2] = c[t2];
    }
  } else if (w == 1 && l < NT) {
    yS[l] = y[l * NN + b];
  }

  // per-thread-owned row/col elements (never touch global again)
  float wrt = Wrec[tid * NN + b];    // W_rec[tid][b]
  float wot = Wout[tid * NN + b];    // W_out[tid][b]
  float po  = Pout[b * NN + tid];    // P_o[b][tid]

  // ---- prologue: h_0 = tanh(0.9 a0 + 0.1 (tanh(a0)@W_rec + x_0@W_in)) ----
  float a_run;
  {
    float v0[1] = { tanhf(a0[tid]) * wrt };
    block_reduceK<1>(v0, red3[1], w, l);   // also fences xwS/yS
    a_run = 0.9f * a0[b] + 0.1f * (v0[0] + xwS[0]);
    if (tid == 0)
      __hip_atomic_store(&ws->hslot[b], packf(tanhf(a_run), 1u),
                         __ATOMIC_RELAXED, __HIP_MEMORY_SCOPE_AGENT);
  }

  // ---- P_GG slice b, row `tid`: 48 named float4 regs (loads overlap h0 RT) ----
  #define SDECL(r) float4 s##r;
  REP48(SDECL)
  {
    const float4* srow = (const float4*)(Pgg + (size_t)b * NN * NN + (size_t)tid * NN);
    #define SLOAD(r) s##r = srow[r];
    REP48(SLOAD)
  }

  // deferred-update state from previous step
  float p_prev = 0.f, rden_prev = 0.f, c_prev = 0.f;
  float e_prev_own = 0.f, k_prev_own = 0.f, e_b_prev = 0.f, k_b_prev = 0.f;

  #pragma unroll 1
  for (int t = 0; t < NT; ++t) {
    const unsigned tag = (unsigned)(t + 1);
    const int par = t & 1;

    // ---- poll h_t; broadcast via LDS ----
    const float h_own = poll_slot(&ws->hslot[tid], tag);
    hsS[tid] = h_own;

    // ---- fused 5-way reduction (its barrier also covers hsS) ----
    float v[5];
    v[0] = h_own * wrt;                       // h . W_r_col_b   (stale)
    v[1] = h_own * (p_prev * e_prev_own);     // h . (p_prev*e_prev)
    v[2] = h_own * wot;                       // h . W_o_col_b   (stale)
    v[3] = h_own * k_prev_own;                // g = h . k_prev
    v[4] = h_own * po;                        // h . P_o_row_b   (stale)
    block_reduceK<5>(v, red5[par], w, l);
    const float ssum_half = v[0] - rden_prev * v[1];         // h . W_r^{t-1}
    const float g   = v[3];
    const float z   = v[2] - c_prev * e_b_prev * g;          // h . W_o^{t-1}
    const float kb  = v[4] - c_prev * k_b_prev * g;          // P_o^{t-1} h
    const float eb  = z - yS[t];
    if (tid == 0) {
      __hip_atomic_store(&ws->ekslot[b][0], packf(eb, tag),
                         __ATOMIC_RELAXED, __HIP_MEMORY_SCOPE_AGENT);
      __hip_atomic_store(&ws->ekslot[b][1], packf(kb, tag),
                         __ATOMIC_RELAXED, __HIP_MEMORY_SCOPE_AGENT);
      out[t * NN + b] = z;
    }
    if (t == NT - 1) break;                   // final outputs published; done

    // ---- lazy row updates (now "through t-1"); off critical path ----
    wrt -= rden_prev * p_prev * e_prev_own;
    wot -= c_prev * k_prev_own * e_b_prev;
    po  -= c_prev * k_b_prev  * k_prev_own;

    // ---- Phase C: p = S_row . h_t (4 independent FMA chains); hides ek RT ----
    const float4* h4 = (const float4*)hsS;
    float4 acc = make_float4(0.f, 0.f, 0.f, 0.f);
    #define PHC(r) { const float4 hv = h4[r]; \
                     acc.x += s##r.x*hv.x; acc.y += s##r.y*hv.y; \
                     acc.z += s##r.z*hv.z; acc.w += s##r.w*hv.w; }
    REP48(PHC)
    const float p = (acc.x + acc.y) + (acc.z + acc.w);
    phS[tid] = p;                              // fenced by reduce's barrier below

    // ---- poll e_t, k_t ----
    const float2 ek = poll_ek(&ws->ekslot[tid][0], tag);
    const float e_own = ek.x, k_own = ek.y;

    // ---- fused 3-way reduction: hk, corr2, hPh ----
    float u[3];
    u[0] = k_own * h_own;
    u[1] = h_own * p * e_own;
    u[2] = p * h_own;
    block_reduceK<3>(u, red3[par], w, l);
    const float rden = 1.f / (1.f + u[2]);
    const float c1   = 1.f / (1.f + u[0]);

    // ---- a-update + publish h_{t+1} immediately ----
    a_run = 0.9f * a_run + 0.1f * (ssum_half - rden * u[1] + xwS[t + 1]);
    if (tid == 0)
      __hip_atomic_store(&ws->hslot[b], packf(tanhf(a_run), tag + 1u),
                         __ATOMIC_RELAXED, __HIP_MEMORY_SCOPE_AGENT);

    // ---- Phase D: S -= (rden*p) * Ph  (off critical path; hides h RT) ----
    const float rv = rden * p;
    const float4* ph4 = (const float4*)phS;
    #define PHD(r) { const float4 pv = ph4[r]; \
                     s##r.x -= rv*pv.x; s##r.y -= rv*pv.y; \
                     s##r.z -= rv*pv.z; s##r.w -= rv*pv.w; }
    REP48(PHD)

    // ---- roll deferred state ----
    p_prev = p; rden_prev = rden; c_prev = c1;
    e_prev_own = e_own; k_prev_own = k_own; e_b_prev = eb; k_b_prev = kb;
  }
}

extern "C" void kernel_launch(void* const* d_in, const int* in_sizes, int n_in,
                              void* d_out, int out_size, void* d_ws, size_t ws_size,
                              hipStream_t stream) {
  const float* x    = (const float*)d_in[0];
  const float* y    = (const float*)d_in[1];
  const float* Win  = (const float*)d_in[2];
  const float* Wrec = (const float*)d_in[3];
  const float* Wout = (const float*)d_in[4];
  const float* a0   = (const float*)d_in[5];
  const float* Pout = (const float*)d_in[6];
  const float* Pgg  = (const float*)d_in[7];
  float* out = (float*)d_out;
  WS* ws = (WS*)d_ws;
  (void)in_sizes; (void)n_in; (void)out_size; (void)ws_size;

  // reset all tags each call (deterministic across graph replays)
  hipMemsetAsync(ws, 0, sizeof(WS), stream);
  force_persistent<<<NN, BLK, 0, stream>>>(x, y, Win, Wrec, Wout, a0, Pout, Pgg, out, ws);
}